// Round 1
// baseline (10284.056 us; speedup 1.0000x reference)
//
#include <hip/hip_runtime.h>
#include <hip/hip_bf16.h>

#define E_EDGES 800000
#define N_NODES_ 50000
#define EPS_ 1e-5f

typedef float f32x4 __attribute__((ext_vector_type(4)));
typedef short s16x8 __attribute__((ext_vector_type(8)));

// workspace layout (float offsets)
#define OFF_AGG   0                            // [N*88] segsum of g
#define OFF_CNT   (N_NODES_ * 88)              // [N] edge counts (float)
#define OFF_M     (OFF_CNT + N_NODES_)         // [88*88] G^T G
#define OFF_CS    (OFF_M + 88 * 88)            // [88] column sums of G
#define OFF_V     (OFF_CS + 88)                // [88*128] M @ W1
#define OFF_S     (OFF_V + 88 * 128)           // [128] bn scale
#define OFF_T     (OFF_S + 128)                // [128] bn shift
#define ZERO_FLOATS (OFF_CS + 88)              // agg+cnt+M+cs must be zeroed

// ---------------------------------------------------------------------------
// Fused edge pass: one streaming read of edge_attr.
//  - scatter-atomic g (88 fp32) into agg88[row], count into cnt[row]
//  - stage 128-edge x 96-feat bf16 tile in LDS, accumulate M = G^T G via MFMA
// Output M is symmetric => immune to any A/B-operand transposition ambiguity.
// ---------------------------------------------------------------------------
__global__ __launch_bounds__(256, 2)
void edge_kernel(const float* __restrict__ x, const int* __restrict__ eidx,
                 const float* __restrict__ ea, float* __restrict__ agg,
                 float* __restrict__ cnt, float* __restrict__ M)
{
    __shared__ short Gs[128 * 98];     // [edge][feat], row stride 98 (bank-spread)
    __shared__ int rowL[128];
    __shared__ int colL[128];

    const int tid  = threadIdx.x;
    const int lane = tid & 63;
    const int wave = tid >> 6;         // 0..3
    const int m    = lane & 15;        // feature-within-group
    const int q    = lane >> 4;        // 0..3 (k-quad)

    f32x4 acc[9];
#pragma unroll
    for (int i = 0; i < 9; ++i) acc[i] = (f32x4){0.f, 0.f, 0.f, 0.f};

    const int n_tiles = E_EDGES / 128; // 6250 exact
    for (int tile = blockIdx.x; tile < n_tiles; tile += gridDim.x) {
        const int ebase = tile * 128;
        __syncthreads();               // protect LDS reuse from previous tile
        if (tid < 128) {
            int r = eidx[ebase + tid];
            int c = eidx[E_EDGES + ebase + tid];
            rowL[tid] = r;
            colL[tid] = c;
            atomicAdd(&cnt[r], 1.0f);
        }
        __syncthreads();

        // stage 128x96 elements (f>=88 zero-padded) + scatter-atomic to agg88
#pragma unroll
        for (int i = 0; i < 48; ++i) {
            int idx = tid + i * 256;   // 0..12287
            int e   = idx / 96;
            int f   = idx - e * 96;
            float v = 0.f;
            if (f < 4)        v = x[colL[e] * 4 + f];
            else if (f < 88)  v = ea[(ebase + e) * 84 + (f - 4)];
            __hip_bfloat16 h = __float2bfloat16(v);
            Gs[e * 98 + f] = *reinterpret_cast<short*>(&h);
            if (f < 88) atomicAdd(&agg[rowL[e] * 88 + f], v);
        }
        __syncthreads();

        // M accumulation: 4 K-steps of 32 edges; 36 16x16 tiles over 96x96,
        // wave w owns tiles {w, w+4, ..., w+32}. frag(p) serves both A and B
        // roles (identical lane mapping for G^T-as-A and G-as-B).
#pragma unroll
        for (int kk = 0; kk < 4; ++kk) {
            const int kbase = kk * 32 + q * 8;
            s16x8 fr[6];
#pragma unroll
            for (int p = 0; p < 6; ++p) {
                s16x8 t;
#pragma unroll
                for (int j = 0; j < 8; ++j)
                    t[j] = Gs[(kbase + j) * 98 + p * 16 + m];
                fr[p] = t;
            }
#pragma unroll
            for (int i = 0; i < 9; ++i) {
                int tno = wave + i * 4;        // 0..35
                int tr = tno / 6, tc = tno - tr * 6;
                acc[i] = __builtin_amdgcn_mfma_f32_16x16x32_bf16(
                             fr[tr], fr[tc], acc[i], 0, 0, 0);
            }
        }
    }

    // flush M partials (C/D layout: col=lane&15, row=q*4+reg  [m89-verified])
#pragma unroll
    for (int i = 0; i < 9; ++i) {
        int tno = wave + i * 4;
        int tr = tno / 6, tc = tno - tr * 6;
        int c = tc * 16 + m;
#pragma unroll
        for (int r0 = 0; r0 < 4; ++r0) {
            int r = tr * 16 + q * 4 + r0;
            if (r < 88 && c < 88) atomicAdd(&M[r * 88 + c], acc[i][r0]);
        }
    }
}

// column sums of G via agg88 (colsum(G) == sum over nodes of segsum(G))
__global__ void colsum_kernel(const float* __restrict__ agg, float* __restrict__ cs)
{
    __shared__ float l[88];
    const int tid = threadIdx.x;
    if (tid < 88) l[tid] = 0.f;
    __syncthreads();
    const int total = N_NODES_ * 88;
    for (int idx = blockIdx.x * blockDim.x + tid; idx < total;
         idx += gridDim.x * blockDim.x) {
        int c = idx % 88;
        atomicAdd(&l[c], agg[idx]);
    }
    __syncthreads();
    if (tid < 88) atomicAdd(&cs[tid], l[tid]);
}

// v = M @ W1   [88 x 128]
__global__ void mv_kernel(const float* __restrict__ M, const float* __restrict__ W1,
                          float* __restrict__ v)
{
    const int a = blockIdx.x;
    const int j = threadIdx.x;
    float acc = 0.f;
    for (int b = 0; b < 88; ++b) acc += M[a * 88 + b] * W1[b * 128 + j];
    v[a * 128 + j] = acc;
}

// per-column BN affine: s = gamma*rsqrt(var+eps), t = beta - mean*s
__global__ void stats_kernel(const float* __restrict__ cs, const float* __restrict__ v,
                             const float* __restrict__ W1, const float* __restrict__ b1,
                             const float* __restrict__ gamma, const float* __restrict__ beta,
                             float* __restrict__ s, float* __restrict__ t)
{
    const int j = threadIdx.x;
    const float invE = 1.0f / (float)E_EDGES;
    float mu = 0.f, eh2 = 0.f;
    for (int a = 0; a < 88; ++a) {
        float w = W1[a * 128 + j];
        mu  += cs[a] * w;
        eh2 += v[a * 128 + j] * w;
    }
    mu *= invE;              // E[g@W1_j]
    eh2 *= invE;             // E[(g@W1_j)^2]
    float var  = eh2 - mu * mu;       // b1 cancels in var
    float mean = mu + b1[j];
    float inv  = rsqrtf(var + EPS_);
    float sj   = gamma[j] * inv;
    s[j] = sj;
    t[j] = beta[j] - mean * sj;
}

// node pass: agg_norm = cnt>0 ? s*(agg88@W1/cnt + b1) + t : 0
//            out = relu([x, agg_norm] @ W2 + b2)
__global__ __launch_bounds__(128)
void node_kernel(const float* __restrict__ x, const float* __restrict__ agg,
                 const float* __restrict__ cnt, const float* __restrict__ W1,
                 const float* __restrict__ b1, const float* __restrict__ W2,
                 const float* __restrict__ b2, const float* __restrict__ s,
                 const float* __restrict__ t, float* __restrict__ out)
{
    __shared__ float aggL[4 * 88];
    __shared__ float featL[4][128];
    __shared__ float cntL[4];
    __shared__ float xL[16];
    const int tid = threadIdx.x;
    const int nbase = blockIdx.x * 4;   // 12500 blocks * 4 nodes = 50000 exact

    for (int i = tid; i < 352; i += 128) aggL[i] = agg[nbase * 88 + i];
    if (tid < 4)  cntL[tid] = cnt[nbase + tid];
    if (tid < 16) xL[tid] = x[nbase * 4 + tid];
    __syncthreads();

    {   // phase 1: 4 nodes x 128 cols of agg@W1
        const int j = tid;
        float a0 = 0.f, a1 = 0.f, a2 = 0.f, a3 = 0.f;
        for (int a = 0; a < 88; ++a) {
            float w = W1[a * 128 + j];
            a0 += aggL[a]       * w;
            a1 += aggL[88 + a]  * w;
            a2 += aggL[176 + a] * w;
            a3 += aggL[264 + a] * w;
        }
        const float sj = s[j], tj = t[j], bj = b1[j];
        float accs[4] = {a0, a1, a2, a3};
#pragma unroll
        for (int n = 0; n < 4; ++n) {
            float c = cntL[n];
            featL[n][j] = (c > 0.f) ? (sj * (accs[n] / c + bj) + tj) : 0.f;
        }
    }
    __syncthreads();

    {   // phase 2: [x, feat] @ W2 + b2, relu
        const int jc = tid & 63;
        const int nh = tid >> 6;        // 0 -> nodes 0,1 ; 1 -> nodes 2,3
#pragma unroll
        for (int h = 0; h < 2; ++h) {
            const int n = nh * 2 + h;
            float acc = b2[jc];
#pragma unroll
            for (int k = 0; k < 4; ++k) acc += xL[n * 4 + k] * W2[k * 64 + jc];
            for (int k = 0; k < 128; ++k)
                acc += featL[n][k] * W2[(4 + k) * 64 + jc];
            out[(nbase + n) * 64 + jc] = fmaxf(acc, 0.f);
        }
    }
}

extern "C" void kernel_launch(void* const* d_in, const int* in_sizes, int n_in,
                              void* d_out, int out_size, void* d_ws, size_t ws_size,
                              hipStream_t stream)
{
    const float* x     = (const float*)d_in[0];
    const int*   eidx  = (const int*)d_in[1];
    const float* ea    = (const float*)d_in[2];
    const float* W1    = (const float*)d_in[3];
    const float* b1    = (const float*)d_in[4];
    const float* gamma = (const float*)d_in[5];
    const float* beta  = (const float*)d_in[6];
    const float* W2    = (const float*)d_in[7];
    const float* b2    = (const float*)d_in[8];

    float* ws  = (float*)d_ws;
    float* agg = ws + OFF_AGG;
    float* cnt = ws + OFF_CNT;
    float* M   = ws + OFF_M;
    float* cs  = ws + OFF_CS;
    float* v   = ws + OFF_V;
    float* s   = ws + OFF_S;
    float* t   = ws + OFF_T;
    float* out = (float*)d_out;

    hipMemsetAsync(d_ws, 0, (size_t)ZERO_FLOATS * sizeof(float), stream);
    edge_kernel<<<625, 256, 0, stream>>>(x, eidx, ea, agg, cnt, M);
    colsum_kernel<<<256, 256, 0, stream>>>(agg, cs);
    mv_kernel<<<88, 128, 0, stream>>>(M, W1, v);
    stats_kernel<<<1, 128, 0, stream>>>(cs, v, W1, b1, gamma, beta, s, t);
    node_kernel<<<12500, 128, 0, stream>>>(x, agg, cnt, W1, b1, W2, b2, s, t, out);
}

// Round 2
// 8205.471 us; speedup vs baseline: 1.2533x; 1.2533x over previous
//
#include <hip/hip_runtime.h>
#include <hip/hip_bf16.h>

#define E_EDGES 800000
#define N_NODES_ 50000
#define EPS_ 1e-5f
#define N_SCAN_BLOCKS 49   // ceil(50000/1024)

typedef float f32x4 __attribute__((ext_vector_type(4)));
typedef short s16x8 __attribute__((ext_vector_type(8)));

// ---- workspace layout (4-byte word offsets) ----
#define OFF_M      0                          // [88*88] fp32, atomically accumulated
#define OFF_CS     (88 * 88)                  // [88] fp32 col sums
#define OFF_CNT    (OFF_CS + 88)              // [N] int histogram (atomics)
#define ZERO_WORDS (OFF_CNT + N_NODES_)       // zero M + cs + cnt
#define OFF_AGG    ZERO_WORDS                 // [N*88] fp32 (written, no zero needed)
#define OFF_CUR    (OFF_AGG + N_NODES_ * 88)  // [N] int scan/cursor
#define OFF_PART   (OFF_CUR + N_NODES_)       // [64] int scan partials
#define OFF_PERM   (OFF_PART + 64)            // [E] int edge permutation
#define OFF_V      (OFF_PERM + E_EDGES)       // [88*128] fp32 M@W1
#define OFF_S      (OFF_V + 88 * 128)         // [128]
#define OFF_T      (OFF_S + 128)              // [128]

// ---------------------------------------------------------------------------
// Streaming M = G^T G via MFMA (no scatter). One coalesced read of edge_attr.
// ---------------------------------------------------------------------------
__global__ __launch_bounds__(256, 2)
void m_kernel(const float* __restrict__ x, const int* __restrict__ eidx,
              const float* __restrict__ ea, float* __restrict__ M)
{
    __shared__ short Gs[128 * 98];
    __shared__ int colL[128];

    const int tid  = threadIdx.x;
    const int lane = tid & 63;
    const int wave = tid >> 6;
    const int m    = lane & 15;
    const int q    = lane >> 4;

    f32x4 acc[9];
#pragma unroll
    for (int i = 0; i < 9; ++i) acc[i] = (f32x4){0.f, 0.f, 0.f, 0.f};

    const int n_tiles = E_EDGES / 128; // 6250
    for (int tile = blockIdx.x; tile < n_tiles; tile += gridDim.x) {
        const int ebase = tile * 128;
        __syncthreads();
        if (tid < 128) colL[tid] = eidx[E_EDGES + ebase + tid];
        __syncthreads();

#pragma unroll
        for (int i = 0; i < 48; ++i) {
            int idx = tid + i * 256;
            int e   = idx / 96;
            int f   = idx - e * 96;
            float v = 0.f;
            if (f < 4)        v = x[colL[e] * 4 + f];
            else if (f < 88)  v = ea[(ebase + e) * 84 + (f - 4)];
            __hip_bfloat16 h = __float2bfloat16(v);
            Gs[e * 98 + f] = *reinterpret_cast<short*>(&h);
        }
        __syncthreads();

#pragma unroll
        for (int kk = 0; kk < 4; ++kk) {
            const int kbase = kk * 32 + q * 8;
            s16x8 fr[6];
#pragma unroll
            for (int p = 0; p < 6; ++p) {
                s16x8 t;
#pragma unroll
                for (int j = 0; j < 8; ++j)
                    t[j] = Gs[(kbase + j) * 98 + p * 16 + m];
                fr[p] = t;
            }
#pragma unroll
            for (int i = 0; i < 9; ++i) {
                int tno = wave + i * 4;
                int tr = tno / 6, tc = tno - tr * 6;
                acc[i] = __builtin_amdgcn_mfma_f32_16x16x32_bf16(
                             fr[tr], fr[tc], acc[i], 0, 0, 0);
            }
        }
    }

#pragma unroll
    for (int i = 0; i < 9; ++i) {
        int tno = wave + i * 4;
        int tr = tno / 6, tc = tno - tr * 6;
        int c = tc * 16 + m;
#pragma unroll
        for (int r0 = 0; r0 < 4; ++r0) {
            int r = tr * 16 + q * 4 + r0;
            if (r < 88 && c < 88) atomicAdd(&M[r * 88 + c], acc[i][r0]);
        }
    }
}

// ---- counting sort: histogram -> scan -> scatter ----
__global__ void hist_kernel(const int* __restrict__ eidx, int* __restrict__ cnt)
{
    int e = blockIdx.x * 256 + threadIdx.x;
    if (e < E_EDGES) atomicAdd(&cnt[eidx[e]], 1);
}

__global__ void scan1_kernel(const int* __restrict__ cnt, int* __restrict__ partial)
{
    __shared__ int l[1024];
    int i = blockIdx.x * 1024 + threadIdx.x;
    l[threadIdx.x] = (i < N_NODES_) ? cnt[i] : 0;
    __syncthreads();
    for (int s = 512; s > 0; s >>= 1) {
        if (threadIdx.x < s) l[threadIdx.x] += l[threadIdx.x + s];
        __syncthreads();
    }
    if (threadIdx.x == 0) partial[blockIdx.x] = l[0];
}

__global__ void scan2_kernel(int* __restrict__ partial)
{
    if (threadIdx.x == 0) {
        int acc = 0;
        for (int i = 0; i < N_SCAN_BLOCKS; ++i) {
            int t = partial[i]; partial[i] = acc; acc += t;
        }
    }
}

__global__ void scan3_kernel(const int* __restrict__ cnt, const int* __restrict__ partial,
                             int* __restrict__ cursor)
{
    __shared__ int l[1024];
    int i = blockIdx.x * 1024 + threadIdx.x;
    int v = (i < N_NODES_) ? cnt[i] : 0;
    l[threadIdx.x] = v;
    __syncthreads();
    for (int s = 1; s < 1024; s <<= 1) {
        int t = (threadIdx.x >= s) ? l[threadIdx.x - s] : 0;
        __syncthreads();
        l[threadIdx.x] += t;
        __syncthreads();
    }
    if (i < N_NODES_) cursor[i] = partial[blockIdx.x] + l[threadIdx.x] - v; // exclusive
}

__global__ void scatter_kernel(const int* __restrict__ eidx, int* __restrict__ cursor,
                               int* __restrict__ perm)
{
    int e = blockIdx.x * 256 + threadIdx.x;
    if (e < E_EDGES) {
        int pos = atomicAdd(&cursor[eidx[e]], 1);
        perm[pos] = e;
    }
}

// ---------------------------------------------------------------------------
// CSR aggregation: one wave per node, lanes own feature columns. No atomics.
// After scatter, cursor[n] == end; start = end - cnt[n].
// ---------------------------------------------------------------------------
__global__ __launch_bounds__(256)
void agg_kernel(const float* __restrict__ x, const int* __restrict__ eidx,
                const float* __restrict__ ea, const int* __restrict__ perm,
                const int* __restrict__ cursor, const int* __restrict__ cnt,
                float* __restrict__ agg)
{
    const int wid  = (blockIdx.x * 256 + threadIdx.x) >> 6;
    const int lane = threadIdx.x & 63;
    if (wid >= N_NODES_) return;
    const int end   = cursor[wid];
    const int start = end - cnt[wid];
    float a0 = 0.f, a1 = 0.f;
    for (int i = start; i < end; ++i) {
        int e = perm[i];
        int col = eidx[E_EDGES + e];
        const float* eaptr = ea + e * 84;
        float v0 = (lane < 4) ? x[col * 4 + lane] : eaptr[lane - 4];
        a0 += v0;
        if (lane < 24) a1 += eaptr[60 + lane];
    }
    agg[wid * 88 + lane] = a0;
    if (lane < 24) agg[wid * 88 + 64 + lane] = a1;
}

// cs[f] = sum over nodes of agg[n][f]
__global__ void colsum_kernel(const float* __restrict__ agg, float* __restrict__ cs)
{
    const int f = threadIdx.x;
    if (f >= 88) return;
    float a = 0.f;
    for (int n = blockIdx.x; n < N_NODES_; n += gridDim.x) a += agg[n * 88 + f];
    atomicAdd(&cs[f], a);
}

// v = M @ W1   [88 x 128]
__global__ void mv_kernel(const float* __restrict__ M, const float* __restrict__ W1,
                          float* __restrict__ v)
{
    const int a = blockIdx.x;
    const int j = threadIdx.x;
    float acc = 0.f;
    for (int b = 0; b < 88; ++b) acc += M[a * 88 + b] * W1[b * 128 + j];
    v[a * 128 + j] = acc;
}

__global__ void stats_kernel(const float* __restrict__ cs, const float* __restrict__ v,
                             const float* __restrict__ W1, const float* __restrict__ b1,
                             const float* __restrict__ gamma, const float* __restrict__ beta,
                             float* __restrict__ s, float* __restrict__ t)
{
    const int j = threadIdx.x;
    const float invE = 1.0f / (float)E_EDGES;
    float mu = 0.f, eh2 = 0.f;
    for (int a = 0; a < 88; ++a) {
        float w = W1[a * 128 + j];
        mu  += cs[a] * w;
        eh2 += v[a * 128 + j] * w;
    }
    mu *= invE;
    eh2 *= invE;
    float var  = eh2 - mu * mu;
    float mean = mu + b1[j];
    float inv  = rsqrtf(var + EPS_);
    float sj   = gamma[j] * inv;
    s[j] = sj;
    t[j] = beta[j] - mean * sj;
}

__global__ __launch_bounds__(128)
void node_kernel(const float* __restrict__ x, const float* __restrict__ agg,
                 const int* __restrict__ cnt, const float* __restrict__ W1,
                 const float* __restrict__ b1, const float* __restrict__ W2,
                 const float* __restrict__ b2, const float* __restrict__ s,
                 const float* __restrict__ t, float* __restrict__ out)
{
    __shared__ float aggL[4 * 88];
    __shared__ float featL[4][128];
    __shared__ float cntL[4];
    __shared__ float xL[16];
    const int tid = threadIdx.x;
    const int nbase = blockIdx.x * 4;

    for (int i = tid; i < 352; i += 128) aggL[i] = agg[nbase * 88 + i];
    if (tid < 4)  cntL[tid] = (float)cnt[nbase + tid];
    if (tid < 16) xL[tid] = x[nbase * 4 + tid];
    __syncthreads();

    {
        const int j = tid;
        float a0 = 0.f, a1 = 0.f, a2 = 0.f, a3 = 0.f;
        for (int a = 0; a < 88; ++a) {
            float w = W1[a * 128 + j];
            a0 += aggL[a]       * w;
            a1 += aggL[88 + a]  * w;
            a2 += aggL[176 + a] * w;
            a3 += aggL[264 + a] * w;
        }
        const float sj = s[j], tj = t[j], bj = b1[j];
        float accs[4] = {a0, a1, a2, a3};
#pragma unroll
        for (int n = 0; n < 4; ++n) {
            float c = cntL[n];
            featL[n][j] = (c > 0.f) ? (sj * (accs[n] / c + bj) + tj) : 0.f;
        }
    }
    __syncthreads();

    {
        const int jc = tid & 63;
        const int nh = tid >> 6;
#pragma unroll
        for (int h = 0; h < 2; ++h) {
            const int n = nh * 2 + h;
            float acc = b2[jc];
#pragma unroll
            for (int k = 0; k < 4; ++k) acc += xL[n * 4 + k] * W2[k * 64 + jc];
            for (int k = 0; k < 128; ++k)
                acc += featL[n][k] * W2[(4 + k) * 64 + jc];
            out[(nbase + n) * 64 + jc] = fmaxf(acc, 0.f);
        }
    }
}

extern "C" void kernel_launch(void* const* d_in, const int* in_sizes, int n_in,
                              void* d_out, int out_size, void* d_ws, size_t ws_size,
                              hipStream_t stream)
{
    const float* x     = (const float*)d_in[0];
    const int*   eidx  = (const int*)d_in[1];
    const float* ea    = (const float*)d_in[2];
    const float* W1    = (const float*)d_in[3];
    const float* b1    = (const float*)d_in[4];
    const float* gamma = (const float*)d_in[5];
    const float* beta  = (const float*)d_in[6];
    const float* W2    = (const float*)d_in[7];
    const float* b2    = (const float*)d_in[8];

    float* ws   = (float*)d_ws;
    float* M    = ws + OFF_M;
    float* cs   = ws + OFF_CS;
    int*   cnt  = (int*)(ws + OFF_CNT);
    float* agg  = ws + OFF_AGG;
    int*   cur  = (int*)(ws + OFF_CUR);
    int*   part = (int*)(ws + OFF_PART);
    int*   perm = (int*)(ws + OFF_PERM);
    float* v    = ws + OFF_V;
    float* s    = ws + OFF_S;
    float* t    = ws + OFF_T;
    float* out  = (float*)d_out;

    hipMemsetAsync(d_ws, 0, (size_t)ZERO_WORDS * sizeof(float), stream);

    hist_kernel<<<(E_EDGES + 255) / 256, 256, 0, stream>>>(eidx, cnt);
    scan1_kernel<<<N_SCAN_BLOCKS, 1024, 0, stream>>>(cnt, part);
    scan2_kernel<<<1, 64, 0, stream>>>(part);
    scan3_kernel<<<N_SCAN_BLOCKS, 1024, 0, stream>>>(cnt, part, cur);
    scatter_kernel<<<(E_EDGES + 255) / 256, 256, 0, stream>>>(eidx, cur, perm);

    m_kernel<<<1250, 256, 0, stream>>>(x, eidx, ea, M);
    agg_kernel<<<(N_NODES_ * 64 + 255) / 256, 256, 0, stream>>>(
        x, eidx, ea, perm, cur, cnt, agg);

    colsum_kernel<<<512, 96, 0, stream>>>(agg, cs);
    mv_kernel<<<88, 128, 0, stream>>>(M, W1, v);
    stats_kernel<<<1, 128, 0, stream>>>(cs, v, W1, b1, gamma, beta, s, t);
    node_kernel<<<12500, 128, 0, stream>>>(x, agg, cnt, W1, b1, W2, b2, s, t, out);
}

// Round 3
// 984.974 us; speedup vs baseline: 10.4409x; 8.3306x over previous
//
#include <hip/hip_runtime.h>
#include <hip/hip_bf16.h>

#define E_EDGES 800000
#define N_NODES_ 50000
#define EPS_ 1e-5f
#define N_SCAN_BLOCKS 49   // ceil(50000/1024)

typedef float f32x4 __attribute__((ext_vector_type(4)));
typedef short s16x8 __attribute__((ext_vector_type(8)));

// ---- workspace layout (4-byte word offsets) ----
#define OFF_M      0                          // [88*88] fp32, atomically accumulated
#define OFF_CS     (88 * 88)                  // [88] fp32 col sums
#define OFF_CNT    (OFF_CS + 88)              // [N] int histogram (atomics)
#define ZERO_WORDS (OFF_CNT + N_NODES_)       // zero M + cs + cnt
#define OFF_AGG    ZERO_WORDS                 // [N*88] fp32 (written, no zero needed)
#define OFF_CUR    (OFF_AGG + N_NODES_ * 88)  // [N] int scan/cursor
#define OFF_PART   (OFF_CUR + N_NODES_)       // [64] int scan partials
#define OFF_PERM   (OFF_PART + 64)            // [E] int edge permutation
#define OFF_V      (OFF_PERM + E_EDGES)       // [88*128] fp32 M@W1
#define OFF_S      (OFF_V + 88 * 128)         // [128]
#define OFF_T      (OFF_S + 128)              // [128]

// ---------------------------------------------------------------------------
// M = G^T G via MFMA. Transposed LDS tile Gs_t[feat][edge] (stride 136 shorts,
// 272 B = 17*16 -> b128-aligned rows). Upper-triangular 16x16 tiles only (21),
// hardcoded per wave so fr[] indices are compile-time (no dynamic VGPR index).
// ---------------------------------------------------------------------------
__global__ __launch_bounds__(256, 4)
void m_kernel(const float* __restrict__ x, const int* __restrict__ eidx,
              const float* __restrict__ ea, float* __restrict__ M)
{
    __shared__ __align__(16) short Gs_t[96 * 136];

    const int tid  = threadIdx.x;
    const int lane = tid & 63;
    const int wave = tid >> 6;         // 0..3
    const int m    = lane & 15;
    const int q    = lane >> 4;        // 0..3

    f32x4 acc[6];
#pragma unroll
    for (int i = 0; i < 6; ++i) acc[i] = (f32x4){0.f, 0.f, 0.f, 0.f};

    // zero the pad rows 88..95 once (staging never overwrites them)
    {
        int* gz = (int*)&Gs_t[88 * 136];       // 23936 B offset, 4-aligned
        for (int i = tid; i < 8 * 136 / 2; i += 256) gz[i] = 0;
    }

    const int e_s = tid & 127;         // edge within tile for staging
    const int h_s = tid >> 7;          // row half: 0 -> feats 4..45, 1 -> 46..87

    const int n_tiles = E_EDGES / 128; // 6250
    for (int tile = blockIdx.x; tile < n_tiles; tile += gridDim.x) {
        const int ebase = tile * 128;
        __syncthreads();               // previous tile's MFMA reads done

        // x features (rows 0..3): lane-per-edge gather (x is L2-resident)
        if (tid < 128) {
            const int c = eidx[E_EDGES + ebase + tid];
            const float4 xv = *(const float4*)(x + (size_t)c * 4);
            __hip_bfloat16 b0 = __float2bfloat16(xv.x);
            __hip_bfloat16 b1 = __float2bfloat16(xv.y);
            __hip_bfloat16 b2 = __float2bfloat16(xv.z);
            __hip_bfloat16 b3 = __float2bfloat16(xv.w);
            Gs_t[0 * 136 + tid] = *(short*)&b0;
            Gs_t[1 * 136 + tid] = *(short*)&b1;
            Gs_t[2 * 136 + tid] = *(short*)&b2;
            Gs_t[3 * 136 + tid] = *(short*)&b3;
        }

        // edge_attr (rows 4..87): each lane streams half its edge's row
        {
            const float2* earow =
                (const float2*)(ea + (size_t)(ebase + e_s) * 84) + h_s * 21;
#pragma unroll 7
            for (int i = 0; i < 21; ++i) {
                const float2 v = earow[i];
                const int f = 4 + (h_s * 21 + i) * 2;
                __hip_bfloat16 b0 = __float2bfloat16(v.x);
                __hip_bfloat16 b1 = __float2bfloat16(v.y);
                Gs_t[f * 136 + e_s]       = *(short*)&b0;
                Gs_t[(f + 1) * 136 + e_s] = *(short*)&b1;
            }
        }
        __syncthreads();

#pragma unroll
        for (int kk = 0; kk < 4; ++kk) {
            const int kbase = kk * 32 + q * 8;   // byte offset 64kk+16q: 16B aligned
            s16x8 fr[6];
#pragma unroll
            for (int p = 0; p < 6; ++p)
                fr[p] = *reinterpret_cast<const s16x8*>(
                            &Gs_t[(p * 16 + m) * 136 + kbase]);
#define MM(i, a, b) acc[i] = __builtin_amdgcn_mfma_f32_16x16x32_bf16(fr[a], fr[b], acc[i], 0, 0, 0)
            if      (wave == 0) { MM(0,0,0); MM(1,0,4); MM(2,1,3); MM(3,2,3); MM(4,3,4); MM(5,5,5); }
            else if (wave == 1) { MM(0,0,1); MM(1,0,5); MM(2,1,4); MM(3,2,4); MM(4,3,5); }
            else if (wave == 2) { MM(0,0,2); MM(1,1,1); MM(2,1,5); MM(3,2,5); MM(4,4,4); }
            else                { MM(0,0,3); MM(1,1,2); MM(2,2,2); MM(3,3,3); MM(4,4,5); }
#undef MM
        }
    }

    // flush: tile k = wave + 4i over triangular enumeration; mirror off-diag.
    // C/D layout: col = lane&15, row = q*4 + reg  [m89-verified]
    const int nt = (wave == 0) ? 6 : 5;
#pragma unroll
    for (int i = 0; i < 6; ++i) {
        if (i < nt) {
            const int k  = wave + i * 4;
            const int tr = (k >= 20) ? 5 : (k >= 18) ? 4 : (k >= 15) ? 3
                         : (k >= 11) ? 2 : (k >= 6) ? 1 : 0;
            const int S  = (tr == 5) ? 20 : (tr == 4) ? 18 : (tr == 3) ? 15
                         : (tr == 2) ? 11 : (tr == 1) ? 6 : 0;
            const int tc = tr + (k - S);
            const int c  = tc * 16 + m;
#pragma unroll
            for (int r0 = 0; r0 < 4; ++r0) {
                const int r = tr * 16 + q * 4 + r0;
                if (r < 88 && c < 88) {
                    atomicAdd(&M[r * 88 + c], acc[i][r0]);
                    if (tr != tc) atomicAdd(&M[c * 88 + r], acc[i][r0]);
                }
            }
        }
    }
}

// ---- counting sort: histogram -> scan -> scatter ----
__global__ void hist_kernel(const int* __restrict__ eidx, int* __restrict__ cnt)
{
    int e = blockIdx.x * 256 + threadIdx.x;
    if (e < E_EDGES) atomicAdd(&cnt[eidx[e]], 1);
}

__global__ void scan1_kernel(const int* __restrict__ cnt, int* __restrict__ partial)
{
    __shared__ int l[1024];
    int i = blockIdx.x * 1024 + threadIdx.x;
    l[threadIdx.x] = (i < N_NODES_) ? cnt[i] : 0;
    __syncthreads();
    for (int s = 512; s > 0; s >>= 1) {
        if (threadIdx.x < s) l[threadIdx.x] += l[threadIdx.x + s];
        __syncthreads();
    }
    if (threadIdx.x == 0) partial[blockIdx.x] = l[0];
}

__global__ void scan2_kernel(int* __restrict__ partial)
{
    if (threadIdx.x == 0) {
        int acc = 0;
        for (int i = 0; i < N_SCAN_BLOCKS; ++i) {
            int t = partial[i]; partial[i] = acc; acc += t;
        }
    }
}

__global__ void scan3_kernel(const int* __restrict__ cnt, const int* __restrict__ partial,
                             int* __restrict__ cursor)
{
    __shared__ int l[1024];
    int i = blockIdx.x * 1024 + threadIdx.x;
    int v = (i < N_NODES_) ? cnt[i] : 0;
    l[threadIdx.x] = v;
    __syncthreads();
    for (int s = 1; s < 1024; s <<= 1) {
        int t = (threadIdx.x >= s) ? l[threadIdx.x - s] : 0;
        __syncthreads();
        l[threadIdx.x] += t;
        __syncthreads();
    }
    if (i < N_NODES_) cursor[i] = partial[blockIdx.x] + l[threadIdx.x] - v; // exclusive
}

__global__ void scatter_kernel(const int* __restrict__ eidx, int* __restrict__ cursor,
                               int* __restrict__ perm)
{
    int e = blockIdx.x * 256 + threadIdx.x;
    if (e < E_EDGES) {
        int pos = atomicAdd(&cursor[eidx[e]], 1);
        perm[pos] = e;
    }
}

// ---------------------------------------------------------------------------
// CSR aggregation: one wave per node; perm/eidx loads pipelined one iteration
// ahead to break the dependent-load chain. No atomics.
// ---------------------------------------------------------------------------
__global__ __launch_bounds__(256)
void agg_kernel(const float* __restrict__ x, const int* __restrict__ eidx,
                const float* __restrict__ ea, const int* __restrict__ perm,
                const int* __restrict__ cursor, const int* __restrict__ cnt,
                float* __restrict__ agg)
{
    const int wid  = (blockIdx.x * 256 + threadIdx.x) >> 6;
    const int lane = threadIdx.x & 63;
    if (wid >= N_NODES_) return;
    const int end   = cursor[wid];
    const int start = end - cnt[wid];
    float a0 = 0.f, a1 = 0.f;
    if (start < end) {
        int e   = perm[start];
        int col = eidx[E_EDGES + e];
        for (int i = start; i < end; ++i) {
            int e_n = 0, col_n = 0;
            if (i + 1 < end) {
                e_n   = perm[i + 1];
                col_n = eidx[E_EDGES + e_n];
            }
            const float* eaptr = ea + (size_t)e * 84;
            float v0 = (lane < 4) ? x[col * 4 + lane] : eaptr[lane - 4];
            a0 += v0;
            if (lane < 24) a1 += eaptr[60 + lane];
            e = e_n; col = col_n;
        }
    }
    agg[wid * 88 + lane] = a0;
    if (lane < 24) agg[wid * 88 + 64 + lane] = a1;
}

// cs[f] = sum over nodes of agg[n][f]
__global__ void colsum_kernel(const float* __restrict__ agg, float* __restrict__ cs)
{
    const int f = threadIdx.x;
    if (f >= 88) return;
    float a = 0.f;
    for (int n = blockIdx.x; n < N_NODES_; n += gridDim.x) a += agg[n * 88 + f];
    atomicAdd(&cs[f], a);
}

// v = M @ W1   [88 x 128]
__global__ void mv_kernel(const float* __restrict__ M, const float* __restrict__ W1,
                          float* __restrict__ v)
{
    const int a = blockIdx.x;
    const int j = threadIdx.x;
    float acc = 0.f;
    for (int b = 0; b < 88; ++b) acc += M[a * 88 + b] * W1[b * 128 + j];
    v[a * 128 + j] = acc;
}

__global__ void stats_kernel(const float* __restrict__ cs, const float* __restrict__ v,
                             const float* __restrict__ W1, const float* __restrict__ b1,
                             const float* __restrict__ gamma, const float* __restrict__ beta,
                             float* __restrict__ s, float* __restrict__ t)
{
    const int j = threadIdx.x;
    const float invE = 1.0f / (float)E_EDGES;
    float mu = 0.f, eh2 = 0.f;
    for (int a = 0; a < 88; ++a) {
        float w = W1[a * 128 + j];
        mu  += cs[a] * w;
        eh2 += v[a * 128 + j] * w;
    }
    mu *= invE;
    eh2 *= invE;
    float var  = eh2 - mu * mu;
    float mean = mu + b1[j];
    float inv  = rsqrtf(var + EPS_);
    float sj   = gamma[j] * inv;
    s[j] = sj;
    t[j] = beta[j] - mean * sj;
}

__global__ __launch_bounds__(128)
void node_kernel(const float* __restrict__ x, const float* __restrict__ agg,
                 const int* __restrict__ cnt, const float* __restrict__ W1,
                 const float* __restrict__ b1, const float* __restrict__ W2,
                 const float* __restrict__ b2, const float* __restrict__ s,
                 const float* __restrict__ t, float* __restrict__ out)
{
    __shared__ float aggL[4 * 88];
    __shared__ float featL[4][128];
    __shared__ float cntL[4];
    __shared__ float xL[16];
    const int tid = threadIdx.x;
    const int nbase = blockIdx.x * 4;

    for (int i = tid; i < 352; i += 128) aggL[i] = agg[nbase * 88 + i];
    if (tid < 4)  cntL[tid] = (float)cnt[nbase + tid];
    if (tid < 16) xL[tid] = x[nbase * 4 + tid];
    __syncthreads();

    {
        const int j = tid;
        float a0 = 0.f, a1 = 0.f, a2 = 0.f, a3 = 0.f;
        for (int a = 0; a < 88; ++a) {
            float w = W1[a * 128 + j];
            a0 += aggL[a]       * w;
            a1 += aggL[88 + a]  * w;
            a2 += aggL[176 + a] * w;
            a3 += aggL[264 + a] * w;
        }
        const float sj = s[j], tj = t[j], bj = b1[j];
        float accs[4] = {a0, a1, a2, a3};
#pragma unroll
        for (int n = 0; n < 4; ++n) {
            float c = cntL[n];
            featL[n][j] = (c > 0.f) ? (sj * (accs[n] / c + bj) + tj) : 0.f;
        }
    }
    __syncthreads();

    {
        const int jc = tid & 63;
        const int nh = tid >> 6;
#pragma unroll
        for (int h = 0; h < 2; ++h) {
            const int n = nh * 2 + h;
            float acc = b2[jc];
#pragma unroll
            for (int k = 0; k < 4; ++k) acc += xL[n * 4 + k] * W2[k * 64 + jc];
            for (int k = 0; k < 128; ++k)
                acc += featL[n][k] * W2[(4 + k) * 64 + jc];
            out[(nbase + n) * 64 + jc] = fmaxf(acc, 0.f);
        }
    }
}

extern "C" void kernel_launch(void* const* d_in, const int* in_sizes, int n_in,
                              void* d_out, int out_size, void* d_ws, size_t ws_size,
                              hipStream_t stream)
{
    const float* x     = (const float*)d_in[0];
    const int*   eidx  = (const int*)d_in[1];
    const float* ea    = (const float*)d_in[2];
    const float* W1    = (const float*)d_in[3];
    const float* b1    = (const float*)d_in[4];
    const float* gamma = (const float*)d_in[5];
    const float* beta  = (const float*)d_in[6];
    const float* W2    = (const float*)d_in[7];
    const float* b2    = (const float*)d_in[8];

    float* ws   = (float*)d_ws;
    float* M    = ws + OFF_M;
    float* cs   = ws + OFF_CS;
    int*   cnt  = (int*)(ws + OFF_CNT);
    float* agg  = ws + OFF_AGG;
    int*   cur  = (int*)(ws + OFF_CUR);
    int*   part = (int*)(ws + OFF_PART);
    int*   perm = (int*)(ws + OFF_PERM);
    float* v    = ws + OFF_V;
    float* s    = ws + OFF_S;
    float* t    = ws + OFF_T;
    float* out  = (float*)d_out;

    hipMemsetAsync(d_ws, 0, (size_t)ZERO_WORDS * sizeof(float), stream);

    hist_kernel<<<(E_EDGES + 255) / 256, 256, 0, stream>>>(eidx, cnt);
    scan1_kernel<<<N_SCAN_BLOCKS, 1024, 0, stream>>>(cnt, part);
    scan2_kernel<<<1, 64, 0, stream>>>(part);
    scan3_kernel<<<N_SCAN_BLOCKS, 1024, 0, stream>>>(cnt, part, cur);
    scatter_kernel<<<(E_EDGES + 255) / 256, 256, 0, stream>>>(eidx, cur, perm);

    m_kernel<<<1024, 256, 0, stream>>>(x, eidx, ea, M);
    agg_kernel<<<(N_NODES_ * 64 + 255) / 256, 256, 0, stream>>>(
        x, eidx, ea, perm, cur, cnt, agg);

    colsum_kernel<<<512, 96, 0, stream>>>(agg, cs);
    mv_kernel<<<88, 128, 0, stream>>>(M, W1, v);
    stats_kernel<<<1, 128, 0, stream>>>(cs, v, W1, b1, gamma, beta, s, t);
    node_kernel<<<12500, 128, 0, stream>>>(x, agg, cnt, W1, b1, W2, b2, s, t, out);
}

// Round 4
// 921.658 us; speedup vs baseline: 11.1582x; 1.0687x over previous
//
#include <hip/hip_runtime.h>
#include <hip/hip_bf16.h>

#define E_EDGES 800000
#define N_NODES_ 50000
#define EPS_ 1e-5f
#define N_SCAN_BLOCKS 49   // ceil(50000/1024)

#define M_GRID   1250      // 6250 tiles / 1250 blocks = 5 tiles each, exact
#define M_ITERS  5

typedef float f32x4 __attribute__((ext_vector_type(4)));
typedef short s16x8 __attribute__((ext_vector_type(8)));

// ---- workspace layout (4-byte word offsets) ----
#define OFF_M      0                          // [88*88] fp32, atomically accumulated
#define OFF_CS     (88 * 88)                  // [88] fp32 col sums
#define OFF_CNT    (OFF_CS + 88)              // [N] int histogram (atomics)
#define ZERO_WORDS (OFF_CNT + N_NODES_)       // zero M + cs + cnt
#define OFF_AGG    ZERO_WORDS                 // [N*88] fp32 (written, no zero needed)
#define OFF_CUR    (OFF_AGG + N_NODES_ * 88)  // [N] int scan/cursor
#define OFF_PART   (OFF_CUR + N_NODES_)       // [64] int scan partials
#define OFF_PERM   (OFF_PART + 64)            // [E] int edge permutation
#define OFF_V      (OFF_PERM + E_EDGES)       // [88*128] fp32 M@W1
#define OFF_S      (OFF_V + 88 * 128)         // [128]
#define OFF_T      (OFF_S + 128)              // [128]

// ---------------------------------------------------------------------------
// M = G^T G via MFMA. Coalesced staging (contiguous 43KB tile range, float2
// per lane) + register software pipeline: tile t+1 loads in flight during
// tile t's LDS-write + MFMA. Transposed LDS Gs_t[feat][edge], stride 136
// shorts (272B, 16B-aligned rows for ds_read_b128 fragments).
// Upper-triangular 16x16 tiles only (21), hardcoded per wave.
// ---------------------------------------------------------------------------
__global__ __launch_bounds__(256, 3)
void m_kernel(const float* __restrict__ x, const int* __restrict__ eidx,
              const float* __restrict__ ea, float* __restrict__ M)
{
    __shared__ __align__(16) short Gs_t[96 * 136];

    const int tid  = threadIdx.x;
    const int lane = tid & 63;
    const int wave = tid >> 6;         // 0..3
    const int m    = lane & 15;
    const int q    = lane >> 4;        // 0..3

    f32x4 acc[6];
#pragma unroll
    for (int i = 0; i < 6; ++i) acc[i] = (f32x4){0.f, 0.f, 0.f, 0.f};

    // zero pad rows 88..95 once (staging never writes them)
    {
        int* gz = (int*)&Gs_t[88 * 136];
        for (int i = tid; i < 8 * 136 / 2; i += 256) gz[i] = 0;
    }

    // precompute LDS short-index for each of this thread's 21 float2 slots
    unsigned addrL[21];
#pragma unroll
    for (int i = 0; i < 21; ++i) {
        const int d = (i * 256 + tid) * 2;   // dword index in tile, even
        const int e = d / 84;
        const int f = d - e * 84;            // even, <= 82
        addrL[i] = (unsigned)((4 + f) * 136 + e);
    }

    int tile = blockIdx.x;
    // ---- prologue: tile0 in flight ----
    int colA = 0, colB = 0;
    if (tid < 128) colA = eidx[E_EDGES + tile * 128 + tid];
    float2 r[21];
    {
        const float2* tb = (const float2*)ea + (size_t)tile * 5376;
#pragma unroll
        for (int i = 0; i < 21; ++i) r[i] = tb[i * 256 + tid];
    }
    float4 xv = (float4){0.f, 0.f, 0.f, 0.f};
    if (tid < 128) xv = *(const float4*)(x + (size_t)colA * 4);
    if (tid < 128) colB = eidx[E_EDGES + (tile + M_GRID) * 128 + tid];

#pragma unroll 1
    for (int it = 0; it < M_ITERS; ++it) {
        __syncthreads();               // previous tile's MFMA reads done

        // stage x rows 0..3
        if (tid < 128) {
            __hip_bfloat16 b0 = __float2bfloat16(xv.x);
            __hip_bfloat16 b1 = __float2bfloat16(xv.y);
            __hip_bfloat16 b2 = __float2bfloat16(xv.z);
            __hip_bfloat16 b3 = __float2bfloat16(xv.w);
            Gs_t[0 * 136 + tid] = *(short*)&b0;
            Gs_t[1 * 136 + tid] = *(short*)&b1;
            Gs_t[2 * 136 + tid] = *(short*)&b2;
            Gs_t[3 * 136 + tid] = *(short*)&b3;
        }
        // stage ea rows 4..87 (transpose)
#pragma unroll
        for (int i = 0; i < 21; ++i) {
            __hip_bfloat16 b0 = __float2bfloat16(r[i].x);
            __hip_bfloat16 b1 = __float2bfloat16(r[i].y);
            Gs_t[addrL[i]]       = *(short*)&b0;
            Gs_t[addrL[i] + 136] = *(short*)&b1;
        }

        // prefetch next tile (stays in flight through MFMA phase)
        const int next = tile + M_GRID;
        if (it + 1 < M_ITERS) {
            const float2* tbn = (const float2*)ea + (size_t)next * 5376;
#pragma unroll
            for (int i = 0; i < 21; ++i) r[i] = tbn[i * 256 + tid];
            if (tid < 128) xv = *(const float4*)(x + (size_t)colB * 4);
            if (tid < 128 && it + 2 < M_ITERS)
                colB = eidx[E_EDGES + (next + M_GRID) * 128 + tid];
        }
        __syncthreads();

#pragma unroll
        for (int kk = 0; kk < 4; ++kk) {
            const int kbase = kk * 32 + q * 8;
            s16x8 fr[6];
#pragma unroll
            for (int p = 0; p < 6; ++p)
                fr[p] = *reinterpret_cast<const s16x8*>(
                            &Gs_t[(p * 16 + m) * 136 + kbase]);
#define MM(i, a, b) acc[i] = __builtin_amdgcn_mfma_f32_16x16x32_bf16(fr[a], fr[b], acc[i], 0, 0, 0)
            if      (wave == 0) { MM(0,0,0); MM(1,0,4); MM(2,1,3); MM(3,2,3); MM(4,3,4); MM(5,5,5); }
            else if (wave == 1) { MM(0,0,1); MM(1,0,5); MM(2,1,4); MM(3,2,4); MM(4,3,5); }
            else if (wave == 2) { MM(0,0,2); MM(1,1,1); MM(2,1,5); MM(3,2,5); MM(4,4,4); }
            else                { MM(0,0,3); MM(1,1,2); MM(2,2,2); MM(3,3,3); MM(4,4,5); }
#undef MM
        }
        tile = next;
    }

    // flush: tile k = wave + 4i over triangular enumeration; mirror off-diag.
    // C/D layout: col = lane&15, row = q*4 + reg  [m89-verified]
    const int nt = (wave == 0) ? 6 : 5;
#pragma unroll
    for (int i = 0; i < 6; ++i) {
        if (i < nt) {
            const int k  = wave + i * 4;
            const int tr = (k >= 20) ? 5 : (k >= 18) ? 4 : (k >= 15) ? 3
                         : (k >= 11) ? 2 : (k >= 6) ? 1 : 0;
            const int S  = (tr == 5) ? 20 : (tr == 4) ? 18 : (tr == 3) ? 15
                         : (tr == 2) ? 11 : (tr == 1) ? 6 : 0;
            const int tc = tr + (k - S);
            const int c  = tc * 16 + m;
#pragma unroll
            for (int r0 = 0; r0 < 4; ++r0) {
                const int rr = tr * 16 + q * 4 + r0;
                if (rr < 88 && c < 88) {
                    atomicAdd(&M[rr * 88 + c], acc[i][r0]);
                    if (tr != tc) atomicAdd(&M[c * 88 + rr], acc[i][r0]);
                }
            }
        }
    }
}

// ---- counting sort: histogram -> scan -> scatter ----
__global__ void hist_kernel(const int* __restrict__ eidx, int* __restrict__ cnt)
{
    int e = blockIdx.x * 256 + threadIdx.x;
    if (e < E_EDGES) atomicAdd(&cnt[eidx[e]], 1);
}

__global__ void scan1_kernel(const int* __restrict__ cnt, int* __restrict__ partial)
{
    __shared__ int l[1024];
    int i = blockIdx.x * 1024 + threadIdx.x;
    l[threadIdx.x] = (i < N_NODES_) ? cnt[i] : 0;
    __syncthreads();
    for (int s = 512; s > 0; s >>= 1) {
        if (threadIdx.x < s) l[threadIdx.x] += l[threadIdx.x + s];
        __syncthreads();
    }
    if (threadIdx.x == 0) partial[blockIdx.x] = l[0];
}

__global__ void scan2_kernel(int* __restrict__ partial)
{
    if (threadIdx.x == 0) {
        int acc = 0;
        for (int i = 0; i < N_SCAN_BLOCKS; ++i) {
            int t = partial[i]; partial[i] = acc; acc += t;
        }
    }
}

__global__ void scan3_kernel(const int* __restrict__ cnt, const int* __restrict__ partial,
                             int* __restrict__ cursor)
{
    __shared__ int l[1024];
    int i = blockIdx.x * 1024 + threadIdx.x;
    int v = (i < N_NODES_) ? cnt[i] : 0;
    l[threadIdx.x] = v;
    __syncthreads();
    for (int s = 1; s < 1024; s <<= 1) {
        int t = (threadIdx.x >= s) ? l[threadIdx.x - s] : 0;
        __syncthreads();
        l[threadIdx.x] += t;
        __syncthreads();
    }
    if (i < N_NODES_) cursor[i] = partial[blockIdx.x] + l[threadIdx.x] - v; // exclusive
}

__global__ void scatter_kernel(const int* __restrict__ eidx, int* __restrict__ cursor,
                               int* __restrict__ perm)
{
    int e = blockIdx.x * 256 + threadIdx.x;
    if (e < E_EDGES) {
        int pos = atomicAdd(&cursor[eidx[e]], 1);
        perm[pos] = e;
    }
}

// ---------------------------------------------------------------------------
// CSR aggregation: TWO waves per node (halved serial chain, 2x TLP), each
// with depth-2 prefetch of perm/eidx; partials combined via LDS. No atomics.
// ---------------------------------------------------------------------------
__global__ __launch_bounds__(256)
void agg_kernel(const float* __restrict__ x, const int* __restrict__ eidx,
                const float* __restrict__ ea, const int* __restrict__ perm,
                const int* __restrict__ cursor, const int* __restrict__ cnt,
                float* __restrict__ agg)
{
    __shared__ float comb[2][88];
    const int tid  = threadIdx.x;
    const int w    = tid >> 6;
    const int lane = tid & 63;
    const int nloc = w >> 1;           // 0,1
    const int par  = w & 1;            // parity within node
    const int node = blockIdx.x * 2 + nloc;   // 25000 blocks * 2 = 50000 exact

    const int end = cursor[node];
    float a0 = 0.f, a1 = 0.f;
    int i = end - cnt[node] + par;
    if (i < end) {
        int e   = perm[i];
        int col = eidx[E_EDGES + e];
        for (; i < end; i += 2) {
            const float* p = ea + (size_t)e * 84;
            float v0 = (lane < 4) ? x[(size_t)col * 4 + lane] : p[lane - 4];
            float v1 = (lane < 24) ? p[60 + lane] : 0.f;
            int e_n = 0, col_n = 0;
            if (i + 2 < end) {
                e_n   = perm[i + 2];
                col_n = eidx[E_EDGES + e_n];
            }
            a0 += v0;
            a1 += v1;
            e = e_n; col = col_n;
        }
    }
    if (par == 1) {
        comb[nloc][lane] = a0;
        if (lane < 24) comb[nloc][64 + lane] = a1;
    }
    __syncthreads();
    if (par == 0) {
        a0 += comb[nloc][lane];
        if (lane < 24) a1 += comb[nloc][64 + lane];
        agg[(size_t)node * 88 + lane] = a0;
        if (lane < 24) agg[(size_t)node * 88 + 64 + lane] = a1;
    }
}

// cs[f] = sum over nodes of agg[n][f]
__global__ void colsum_kernel(const float* __restrict__ agg, float* __restrict__ cs)
{
    const int f = threadIdx.x;
    if (f >= 88) return;
    float a = 0.f;
    for (int n = blockIdx.x; n < N_NODES_; n += gridDim.x) a += agg[n * 88 + f];
    atomicAdd(&cs[f], a);
}

// v = M @ W1   [88 x 128]
__global__ void mv_kernel(const float* __restrict__ M, const float* __restrict__ W1,
                          float* __restrict__ v)
{
    const int a = blockIdx.x;
    const int j = threadIdx.x;
    float acc = 0.f;
    for (int b = 0; b < 88; ++b) acc += M[a * 88 + b] * W1[b * 128 + j];
    v[a * 128 + j] = acc;
}

__global__ void stats_kernel(const float* __restrict__ cs, const float* __restrict__ v,
                             const float* __restrict__ W1, const float* __restrict__ b1,
                             const float* __restrict__ gamma, const float* __restrict__ beta,
                             float* __restrict__ s, float* __restrict__ t)
{
    const int j = threadIdx.x;
    const float invE = 1.0f / (float)E_EDGES;
    float mu = 0.f, eh2 = 0.f;
    for (int a = 0; a < 88; ++a) {
        float w = W1[a * 128 + j];
        mu  += cs[a] * w;
        eh2 += v[a * 128 + j] * w;
    }
    mu *= invE;
    eh2 *= invE;
    float var  = eh2 - mu * mu;
    float mean = mu + b1[j];
    float inv  = rsqrtf(var + EPS_);
    float sj   = gamma[j] * inv;
    s[j] = sj;
    t[j] = beta[j] - mean * sj;
}

__global__ __launch_bounds__(128)
void node_kernel(const float* __restrict__ x, const float* __restrict__ agg,
                 const int* __restrict__ cnt, const float* __restrict__ W1,
                 const float* __restrict__ b1, const float* __restrict__ W2,
                 const float* __restrict__ b2, const float* __restrict__ s,
                 const float* __restrict__ t, float* __restrict__ out)
{
    __shared__ float aggL[4 * 88];
    __shared__ float featL[4][128];
    __shared__ float cntL[4];
    __shared__ float xL[16];
    const int tid = threadIdx.x;
    const int nbase = blockIdx.x * 4;

    for (int i = tid; i < 352; i += 128) aggL[i] = agg[nbase * 88 + i];
    if (tid < 4)  cntL[tid] = (float)cnt[nbase + tid];
    if (tid < 16) xL[tid] = x[nbase * 4 + tid];
    __syncthreads();

    {
        const int j = tid;
        float a0 = 0.f, a1 = 0.f, a2 = 0.f, a3 = 0.f;
        for (int a = 0; a < 88; ++a) {
            float w = W1[a * 128 + j];
            a0 += aggL[a]       * w;
            a1 += aggL[88 + a]  * w;
            a2 += aggL[176 + a] * w;
            a3 += aggL[264 + a] * w;
        }
        const float sj = s[j], tj = t[j], bj = b1[j];
        float accs[4] = {a0, a1, a2, a3};
#pragma unroll
        for (int n = 0; n < 4; ++n) {
            float c = cntL[n];
            featL[n][j] = (c > 0.f) ? (sj * (accs[n] / c + bj) + tj) : 0.f;
        }
    }
    __syncthreads();

    {
        const int jc = tid & 63;
        const int nh = tid >> 6;
#pragma unroll
        for (int h = 0; h < 2; ++h) {
            const int n = nh * 2 + h;
            float acc = b2[jc];
#pragma unroll
            for (int k = 0; k < 4; ++k) acc += xL[n * 4 + k] * W2[k * 64 + jc];
            for (int k = 0; k < 128; ++k)
                acc += featL[n][k] * W2[(4 + k) * 64 + jc];
            out[(nbase + n) * 64 + jc] = fmaxf(acc, 0.f);
        }
    }
}

extern "C" void kernel_launch(void* const* d_in, const int* in_sizes, int n_in,
                              void* d_out, int out_size, void* d_ws, size_t ws_size,
                              hipStream_t stream)
{
    const float* x     = (const float*)d_in[0];
    const int*   eidx  = (const int*)d_in[1];
    const float* ea    = (const float*)d_in[2];
    const float* W1    = (const float*)d_in[3];
    const float* b1    = (const float*)d_in[4];
    const float* gamma = (const float*)d_in[5];
    const float* beta  = (const float*)d_in[6];
    const float* W2    = (const float*)d_in[7];
    const float* b2    = (const float*)d_in[8];

    float* ws   = (float*)d_ws;
    float* M    = ws + OFF_M;
    float* cs   = ws + OFF_CS;
    int*   cnt  = (int*)(ws + OFF_CNT);
    float* agg  = ws + OFF_AGG;
    int*   cur  = (int*)(ws + OFF_CUR);
    int*   part = (int*)(ws + OFF_PART);
    int*   perm = (int*)(ws + OFF_PERM);
    float* v    = ws + OFF_V;
    float* s    = ws + OFF_S;
    float* t    = ws + OFF_T;
    float* out  = (float*)d_out;

    hipMemsetAsync(d_ws, 0, (size_t)ZERO_WORDS * sizeof(float), stream);

    hist_kernel<<<(E_EDGES + 255) / 256, 256, 0, stream>>>(eidx, cnt);
    scan1_kernel<<<N_SCAN_BLOCKS, 1024, 0, stream>>>(cnt, part);
    scan2_kernel<<<1, 64, 0, stream>>>(part);
    scan3_kernel<<<N_SCAN_BLOCKS, 1024, 0, stream>>>(cnt, part, cur);
    scatter_kernel<<<(E_EDGES + 255) / 256, 256, 0, stream>>>(eidx, cur, perm);

    m_kernel<<<M_GRID, 256, 0, stream>>>(x, eidx, ea, M);
    agg_kernel<<<N_NODES_ / 2, 256, 0, stream>>>(x, eidx, ea, perm, cur, cnt, agg);

    colsum_kernel<<<512, 96, 0, stream>>>(agg, cs);
    mv_kernel<<<88, 128, 0, stream>>>(M, W1, v);
    stats_kernel<<<1, 128, 0, stream>>>(cs, v, W1, b1, gamma, beta, s, t);
    node_kernel<<<12500, 128, 0, stream>>>(x, agg, cnt, W1, b1, W2, b2, s, t, out);
}